// Round 2
// 1211.413 us; speedup vs baseline: 2.1017x; 2.1017x over previous
//
#include <hip/hip_runtime.h>
#include <math.h>

#define NIMG 8
#define CIN  512
#define HF   50
#define WF   64
#define HW   3200
#define NA   9
#define KPER 28800   /* HW*NA per image */
#define PRE  6000
#define POST 300

#define WHT_ELEMS  32768     /* 512*64 */

/* padded NHWC f16 input: rows 52 (row p holds x row p-1; p=0,51 zero),
   cols 66 (col w' holds x col w'-1; w'=0,65 zero), ci contiguous. */
#define XTROWS 52
#define XTCOLS 66
#define XT_ELEMS ((size_t)NIMG * XTROWS * XTCOLS * CIN)   /* 14,057,472 */
#define XT_BYTES (XT_ELEMS * 2)                            /* 28,114,944 */

/* packed weights: [sp2][cob4][tap9][ks16][4096 f16] in LDS-physical tile order */
#define WPK_ELEMS ((size_t)2 * 4 * 9 * 16 * 4096)          /* 4,718,592 */
#define WPK_HALF  (4 * 9 * 16 * 4096)                      /* 2,359,296 */

/* scaling: x' = x*2^8, w' = w*2^14; acc scale 2^22 undone in epilogue */
#define SCALE_X 256.0f
#define SCALE_W 16384.0f
#define INV_SCALE (1.0f / 4194304.0f)   /* 2^-22 */

typedef _Float16 f16x8 __attribute__((ext_vector_type(8)));
typedef float f32x4  __attribute__((ext_vector_type(4)));
typedef unsigned short u16x8 __attribute__((ext_vector_type(8)));

// Base anchors (x1,y1,x2,y2) computed in double, rounded to f32 (matches np.float32 cast)
__constant__ float BASEA[9][4] = {
  {-82.509667991878083f, -37.254833995939042f,  98.509667991878083f,  53.254833995939042f},
  {-173.01933598375617f, -82.509667991878083f, 189.01933598375617f,   98.509667991878083f},
  {-354.03867196751233f, -173.01933598375617f, 370.03867196751233f,  189.01933598375617f},
  { -56.0f,  -56.0f,  72.0f,  72.0f},
  {-120.0f, -120.0f, 136.0f, 136.0f},
  {-248.0f, -248.0f, 264.0f, 264.0f},
  {-37.254833995939042f, -82.509667991878083f,  53.254833995939042f,  98.509667991878083f},
  {-82.509667991878083f, -173.01933598375617f,  98.509667991878083f, 189.01933598375617f},
  {-173.01933598375617f, -354.03867196751233f, 189.01933598375617f,  370.03867196751233f},
};

__device__ __forceinline__ unsigned int ordf(float f) {
  unsigned int u = __float_as_uint(f);
  return (u & 0x80000000u) ? ~u : (u | 0x80000000u);
}

__device__ __forceinline__ unsigned short f2h(float f) {
  union { _Float16 h; unsigned short u; } cv;
  cv.h = (_Float16)f;             /* v_cvt_f16_f32, RNE */
  return cv.u;
}
__device__ __forceinline__ float h2f(unsigned short u) {
  union { _Float16 h; unsigned short u; } cv;
  cv.u = u;
  return (float)cv.h;
}

__device__ __forceinline__ unsigned long long shfl_down_u64(unsigned long long v, int off) {
  unsigned int lo = (unsigned int)(v & 0xFFFFFFFFull);
  unsigned int hi = (unsigned int)(v >> 32);
  lo = __shfl_down(lo, off, 64);
  hi = __shfl_down(hi, off, 64);
  return (((unsigned long long)hi) << 32) | (unsigned long long)lo;
}

__device__ __forceinline__ unsigned long long shfl_xor_u64(unsigned long long v, int m) {
  unsigned int lo = (unsigned int)(v & 0xFFFFFFFFull);
  unsigned int hi = (unsigned int)(v >> 32);
  lo = __shfl_xor(lo, m, 64);
  hi = __shfl_xor(hi, m, 64);
  return (((unsigned long long)hi) << 32) | (unsigned long long)lo;
}

// ---------------------------------------------------------------------------
// Prep 0: zero xTh/xTl entirely (halos stay zero; interior overwritten next).
// ---------------------------------------------------------------------------
__global__ __launch_bounds__(256) void k_zerox(float4* __restrict__ a,
                                               float4* __restrict__ b) {
  const int tot = (int)(XT_BYTES / 16);   /* 1,757,184 */
  const int stride = gridDim.x * 256;
  const float4 z = make_float4(0.f, 0.f, 0.f, 0.f);
  for (int i = blockIdx.x * 256 + threadIdx.x; i < tot; i += stride) {
    a[i] = z;
    b[i] = z;
  }
}

// ---------------------------------------------------------------------------
// Prep A: x NCHW f32 -> padded NHWC f16 hi/lo of x*2^8.  LDS-transposed,
// coalesced both sides.  block = (n*50 + hrow)*4 + cichunk.
// g = x*256 is exact (pow2); g - hi exact (Sterbenz); lo = f16(g - hi).
// ---------------------------------------------------------------------------
__global__ __launch_bounds__(256) void k_prepxT(const float4* __restrict__ x4,
                                                unsigned short* __restrict__ xh,
                                                unsigned short* __restrict__ xl) {
  __shared__ float tile[128][65];
  const int b = blockIdx.x;
  const int cic = b & 3;
  const int rest = b >> 2;
  const int hrow = rest % 50;
  const int n = rest / 50;
  const int t = threadIdx.x;
#pragma unroll
  for (int jj = 0; jj < 8; ++jj) {
    const int e = t + 256 * jj;              /* 0..2047 */
    const int row = e >> 4, c4 = e & 15;
    const float4 v = x4[(((size_t)(n * CIN + cic * 128 + row) * HF + hrow) << 4) + c4];
    tile[row][c4 * 4 + 0] = v.x;
    tile[row][c4 * 4 + 1] = v.y;
    tile[row][c4 * 4 + 2] = v.z;
    tile[row][c4 * 4 + 3] = v.w;
  }
  __syncthreads();
#pragma unroll
  for (int jj = 0; jj < 4; ++jj) {
    const int e = t + 256 * jj;              /* 0..1023 */
    const int w = e >> 4, c8 = e & 15;
    const size_t base = ((size_t)((n * XTROWS + (hrow + 1)) * XTCOLS) + (w + 1)) * CIN
                        + cic * 128 + c8 * 8;
    u16x8 hv, lv;
#pragma unroll
    for (int u = 0; u < 8; ++u) {
      const float g = tile[c8 * 8 + u][w] * SCALE_X;
      const unsigned short hh = f2h(g);
      hv[u] = (short)hh;
      lv[u] = (short)f2h(g - h2f(hh));
    }
    *reinterpret_cast<u16x8*>(xh + base) = hv;
    *reinterpret_cast<u16x8*>(xl + base) = lv;
  }
}

// ---------------------------------------------------------------------------
// Prep B: w1 [co][ci][3][3] f32 -> wpk [sp][cob][tap][ks][4096] f16 of w*2^14,
// where the 4096-elem tile is exactly the conv kernel's LDS-physical A-tile
// layout:
//   i = col*32 + slot'*8 + j ;  slot' = s ^ ((col>>1)&3) ;
//   k_local = s*8 + j ; ci = ks*32 + k_local ; co = cob*128 + col.
// ---------------------------------------------------------------------------
__global__ __launch_bounds__(256) void k_prepwPk(const float* __restrict__ w1,
                                                 unsigned short* __restrict__ wpk) {
  const int tot = (int)WPK_ELEMS;
  const int stride = gridDim.x * 256;
  for (int idx = blockIdx.x * 256 + threadIdx.x; idx < tot; idx += stride) {
    const int i = idx & 4095;
    int rest = idx >> 12;
    const int ks = rest & 15; rest >>= 4;
    const int tap = rest % 9; rest /= 9;
    const int cob = rest & 3;
    const int sp = rest >> 2;
    const int col = i >> 5;
    const int slotp = (i >> 3) & 3;
    const int j = i & 7;
    const int s = slotp ^ ((col >> 1) & 3);
    const int ci = ks * 32 + s * 8 + j;
    const int co = cob * 128 + col;
    const float g = w1[((size_t)co * CIN + ci) * 9 + tap] * SCALE_W;
    const unsigned short hh = f2h(g);
    wpk[idx] = sp ? f2h(g - h2f(hh)) : hh;
  }
}

// ---------------------------------------------------------------------------
// Prep C: head weights WHT2[c4][o64][4] + biases bh[64]. (validated r3)
// ---------------------------------------------------------------------------
__global__ __launch_bounds__(256) void k_preph(const float* __restrict__ wc,
                                               const float* __restrict__ bc,
                                               const float* __restrict__ wb,
                                               const float* __restrict__ bb,
                                               float* __restrict__ WHT2,
                                               float* __restrict__ bh) {
  const int TOT = WHT_ELEMS + 64;
  const int stride = gridDim.x * 256;
  for (int idx = blockIdx.x * 256 + threadIdx.x; idx < TOT; idx += stride) {
    if (idx < WHT_ELEMS) {
      int r = idx & 3;
      int o = (idx >> 2) & 63;
      int c = (idx >> 8) * 4 + r;
      float v = 0.0f;
      if (o < 18) v = wc[(size_t)o * CIN + c];
      else if (o < 54) v = wb[(size_t)(o - 18) * CIN + c];
      WHT2[idx] = v;
    } else {
      int o = idx - WHT_ELEMS;
      float v = 0.0f;
      if (o < 18) v = bc[o];
      else if (o < 54) v = bb[o - 18];
      bh[o] = v;
    }
  }
}

// ---------------------------------------------------------------------------
// K1: 3x3 conv 512->512 as implicit GEMM on MFMA, fp32-emulated via scaled-f16
// hi/lo split (Ah*Bh + Ah*Bl + Al*Bh; per-product rel err ~6e-8 RMS, below
// fp32 reduction-reorder noise).  M = co(128/block, 4 cob), N = pos(128/block:
// 2 image rows x 64), K = 9 taps x 512 ci (144 steps of 32).
// 4 waves, 2x2 wave grid, 4x4 16x16x32 fragments per wave.
// Staging: global_load_lds dwordx4 into double-buffered LDS; slot-XOR swizzle
// is pre-applied in the GLOBAL layouts (wpk tiles / per-lane x addresses), so
// LDS dest stays linear and frag ds_read_b128 is >=2-way conflict-free.
// One __syncthreads (vmcnt drain) per k-step; tap-inner order for L2 locality.
// ---------------------------------------------------------------------------
#define GLDS(gp, lp) __builtin_amdgcn_global_load_lds( \
    (const __attribute__((address_space(1))) unsigned int*)(gp), \
    (__attribute__((address_space(3))) unsigned int*)(lp), 16, 0, 0)

__global__ __launch_bounds__(256, 2) void k_convmfma(
    const unsigned short* __restrict__ xh,
    const unsigned short* __restrict__ xl,
    const unsigned short* __restrict__ wpk,
    const float* __restrict__ b1,
    float* __restrict__ feat) {
  __shared__ unsigned short lds[2][4][4096];   /* 64 KiB: [buf][Ah,Al,Bh,Bl] */

  const int pb  = blockIdx.x;        /* 0..199 : n*25 + hb */
  const int cob = blockIdx.y;        /* 0..3   : 128-co block */
  const int n   = pb / 25;
  const int h0  = (pb - n * 25) * 2;
  const int t   = threadIdx.x;
  const int wid = t >> 6;
  const int l   = t & 63;
  const int wm  = wid >> 1;          /* wave M index (co) */
  const int wn  = wid & 1;           /* wave N index (pos row) */

  /* staging constants */
  const int colp = l >> 2;                               /* w within 16-col group */
  const int sB = (((l & 3) ^ ((l >> 3) & 3)) << 3);      /* swizzled k-slot elem off */
  const unsigned short* xsrc = (wid == 3) ? xl : xh;
  const size_t wA_base = (size_t)(wid & 1) * WPK_HALF;

  /* fragment-read constants */
  const int fr = l & 15;
  const int fq = l >> 4;
  const int slotr = ((fq ^ ((fr >> 1) & 3)) << 4);       /* swizzled 16B slot (bytes) */

  f32x4 acc[4][4] = {};

  auto stage = [&](int sbuf, int ti) {
    const int ks  = ti / 9;          /* ci chunk  (slow) */
    const int tap = ti - ks * 9;     /* 3x3 tap   (fast: L2 reuse of x rows) */
    if (wid < 2) {
      /* A tiles (weights): wid0 -> hi, wid1 -> lo; layout is pre-packed. */
      const unsigned short* gp = wpk + wA_base
          + ((size_t)((cob * 9 + tap) * 16 + ks) << 12) + l * 8;
      unsigned short* lp = &lds[sbuf][wid][0];
#pragma unroll
      for (int q = 0; q < 8; ++q)
        GLDS(gp + q * 512, lp + q * 512);
    } else {
      /* B tiles (x patches): wid2 -> hi, wid3 -> lo.
         B[k][pos] for tap (ky,kx): xT[n][h0+(pos>>6)+ky][(pos&63)+kx][ks*32+k] */
      const int ky = (tap * 11) >> 5;       /* tap/3 for 0..8 */
      const int kx = tap - ky * 3;
      const size_t ebase = ((size_t)((n * XTROWS + h0 + ky) * XTCOLS + kx + colp) << 9)
                           + ks * 32 + sB;
      unsigned short* lp = &lds[sbuf][wid][0];
#pragma unroll
      for (int q = 0; q < 8; ++q)
        GLDS(xsrc + ebase + ((size_t)(((q >> 2) * XTCOLS + (q & 3) * 16)) << 9),
             lp + q * 512);
    }
  };

  stage(0, 0);
  __syncthreads();

  int buf = 0;
  for (int ti = 0; ti < 144; ++ti) {
    if (ti < 143) stage(buf ^ 1, ti + 1);   /* issue next-step loads first */

    f16x8 ah[4], al[4], bhf[4], blf[4];
#pragma unroll
    for (int mi = 0; mi < 4; ++mi) {
      const int off = (((wm << 6) + (mi << 4) + fr) << 6) + slotr;
      ah[mi] = *(const f16x8*)((const char*)&lds[buf][0][0] + off);
      al[mi] = *(const f16x8*)((const char*)&lds[buf][1][0] + off);
    }
#pragma unroll
    for (int ni = 0; ni < 4; ++ni) {
      const int off = (((wn << 6) + (ni << 4) + fr) << 6) + slotr;
      bhf[ni] = *(const f16x8*)((const char*)&lds[buf][2][0] + off);
      blf[ni] = *(const f16x8*)((const char*)&lds[buf][3][0] + off);
    }
#pragma unroll
    for (int mi = 0; mi < 4; ++mi)
#pragma unroll
      for (int ni = 0; ni < 4; ++ni) {
        acc[mi][ni] = __builtin_amdgcn_mfma_f32_16x16x32_f16(ah[mi], bhf[ni], acc[mi][ni], 0, 0, 0);
        acc[mi][ni] = __builtin_amdgcn_mfma_f32_16x16x32_f16(ah[mi], blf[ni], acc[mi][ni], 0, 0, 0);
        acc[mi][ni] = __builtin_amdgcn_mfma_f32_16x16x32_f16(al[mi], bhf[ni], acc[mi][ni], 0, 0, 0);
      }
    __syncthreads();                        /* drains vmcnt(0): next buf ready */
    buf ^= 1;
  }

  /* epilogue: rescale 2^-22 + bias + relu, float4 per lane into NHWC feat */
  const int h = h0 + wn;
#pragma unroll
  for (int mi = 0; mi < 4; ++mi) {
    const int co = (cob << 7) + (wm << 6) + (mi << 4) + (fq << 2);
    const float4 bias = *(const float4*)&b1[co];
#pragma unroll
    for (int ni = 0; ni < 4; ++ni) {
      const int w = (ni << 4) + fr;
      float4 v;
      v.x = fmaxf(fmaf(acc[mi][ni][0], INV_SCALE, bias.x), 0.0f);
      v.y = fmaxf(fmaf(acc[mi][ni][1], INV_SCALE, bias.y), 0.0f);
      v.z = fmaxf(fmaf(acc[mi][ni][2], INV_SCALE, bias.z), 0.0f);
      v.w = fmaxf(fmaf(acc[mi][ni][3], INV_SCALE, bias.w), 0.0f);
      *(float4*)(feat + (((size_t)n * HW + h * WF + w) << 9) + co) = v;
    }
  }
}

// ---------------------------------------------------------------------------
// K2: 1x1 heads + softmax-fg + box decode + clip + min-size filter.
// (identical numerics to validated r2 kernel)
// ---------------------------------------------------------------------------
__global__ __launch_bounds__(256) void k_head(const float* __restrict__ feat,
                                              const float* __restrict__ WHT2,
                                              const float* __restrict__ bh,
                                              float* __restrict__ scores,
                                              float4* __restrict__ boxes) {
  __shared__ float fsh[16][512];
  __shared__ float vsh[16][64];
  const int t = threadIdx.x;
  const int wvid = t >> 6;
  const int o = t & 63;
  const int pos0 = blockIdx.x * 16;

  for (int i = t; i < 16 * 512; i += 256)
    fsh[i >> 9][i & 511] = feat[((size_t)pos0 << 9) + i];
  __syncthreads();

  {
    const int p0 = wvid * 4;
    float a0 = 0.f, a1 = 0.f, a2 = 0.f, a3 = 0.f;
    const float4* wp = reinterpret_cast<const float4*>(WHT2);
    const float4* f0 = reinterpret_cast<const float4*>(&fsh[p0 + 0][0]);
    const float4* f1 = reinterpret_cast<const float4*>(&fsh[p0 + 1][0]);
    const float4* f2 = reinterpret_cast<const float4*>(&fsh[p0 + 2][0]);
    const float4* f3 = reinterpret_cast<const float4*>(&fsh[p0 + 3][0]);
#pragma unroll 4
    for (int c4 = 0; c4 < 128; ++c4) {
      float4 w4 = wp[c4 * 64 + o];
      float4 v;
      v = f0[c4];
      a0 = fmaf(w4.x, v.x, a0); a0 = fmaf(w4.y, v.y, a0);
      a0 = fmaf(w4.z, v.z, a0); a0 = fmaf(w4.w, v.w, a0);
      v = f1[c4];
      a1 = fmaf(w4.x, v.x, a1); a1 = fmaf(w4.y, v.y, a1);
      a1 = fmaf(w4.z, v.z, a1); a1 = fmaf(w4.w, v.w, a1);
      v = f2[c4];
      a2 = fmaf(w4.x, v.x, a2); a2 = fmaf(w4.y, v.y, a2);
      a2 = fmaf(w4.z, v.z, a2); a2 = fmaf(w4.w, v.w, a2);
      v = f3[c4];
      a3 = fmaf(w4.x, v.x, a3); a3 = fmaf(w4.y, v.y, a3);
      a3 = fmaf(w4.z, v.z, a3); a3 = fmaf(w4.w, v.w, a3);
    }
    float bv = bh[o];
    vsh[p0 + 0][o] = a0 + bv;
    vsh[p0 + 1][o] = a1 + bv;
    vsh[p0 + 2][o] = a2 + bv;
    vsh[p0 + 3][o] = a3 + bv;
  }
  __syncthreads();

  if (t < 144) {
    const int p2 = t / 9, a = t % 9;
    const int pos = pos0 + p2;
    const int n = pos / HW;
    const int r = pos - n * HW;
    const int ph = r >> 6;
    const int pw = r & 63;

    float l0 = vsh[p2][a * 2];
    float l1 = vsh[p2][a * 2 + 1];
    float m  = fmaxf(l0, l1);
    float e0 = (float)exp((double)__fsub_rn(l0, m));
    float e1 = (float)exp((double)__fsub_rn(l1, m));
    float fg = __fdiv_rn(e1, __fadd_rn(e0, e1));

    float d0 = vsh[p2][18 + a * 4 + 0];
    float d1 = vsh[p2][18 + a * 4 + 1];
    float d2 = vsh[p2][18 + a * 4 + 2];
    float d3 = vsh[p2][18 + a * 4 + 3];

    float sx = (float)(pw * 16);
    float sy = (float)(ph * 16);
    float ax1 = __fadd_rn(BASEA[a][0], sx);
    float ay1 = __fadd_rn(BASEA[a][1], sy);
    float ax2 = __fadd_rn(BASEA[a][2], sx);
    float ay2 = __fadd_rn(BASEA[a][3], sy);
    float aw = __fsub_rn(ax2, ax1);
    float ah = __fsub_rn(ay2, ay1);
    float acx = __fadd_rn(ax1, __fmul_rn(0.5f, aw));
    float acy = __fadd_rn(ay1, __fmul_rn(0.5f, ah));
    float cx = __fadd_rn(__fmul_rn(d0, aw), acx);
    float cy = __fadd_rn(__fmul_rn(d1, ah), acy);
    float pwd = __fmul_rn((float)exp((double)d2), aw);
    float phd = __fmul_rn((float)exp((double)d3), ah);
    float x1 = __fsub_rn(cx, __fmul_rn(0.5f, pwd));
    float y1 = __fsub_rn(cy, __fmul_rn(0.5f, phd));
    float x2 = __fadd_rn(cx, __fmul_rn(0.5f, pwd));
    float y2 = __fadd_rn(cy, __fmul_rn(0.5f, phd));
    x1 = fminf(fmaxf(x1, 0.0f), 1024.0f);
    x2 = fminf(fmaxf(x2, 0.0f), 1024.0f);
    y1 = fminf(fmaxf(y1, 0.0f), 800.0f);
    y2 = fminf(fmaxf(y2, 0.0f), 800.0f);
    float wsz = __fsub_rn(x2, x1);
    float hsz = __fsub_rn(y2, y1);
    float sc = (wsz >= 16.0f && hsz >= 16.0f) ? fg : -__builtin_huge_valf();

    const int idx = n * KPER + r * NA + a;
    scores[idx] = sc;
    boxes[idx] = make_float4(x1, y1, x2, y2);
  }
}

// ---------------------------------------------------------------------------
// K3: exact top-6000 per image via radix select (ties: lowest idx, matching
// lax.top_k stability), compact candidates, compute M2 fallback key.
// ---------------------------------------------------------------------------
__global__ __launch_bounds__(1024) void k_topk(const float* __restrict__ scores,
                                               const float4* __restrict__ boxes,
                                               float4* __restrict__ cbox,
                                               unsigned long long* __restrict__ ckey,
                                               unsigned long long* __restrict__ m2out) {
  const int n = blockIdx.x;
  const int t = threadIdx.x;
  __shared__ unsigned int hist[256];
  __shared__ unsigned int sh_selB, sh_ngt, sh_binc, sh_num;
  __shared__ unsigned long long sh_m2;
  const float* sc = scores + (size_t)n * KPER;

  unsigned int prefix = 0, prefMask = 0, ngt = 0, neq = 0;
  for (int shift = 24; shift >= 0; shift -= 8) {
    if (t < 256) hist[t] = 0;
    __syncthreads();
    for (int i = t; i < KPER; i += 1024) {
      unsigned int u = ordf(sc[i]);
      if ((u & prefMask) == prefix) atomicAdd(&hist[(u >> shift) & 255], 1u);
    }
    __syncthreads();
    if (t == 0) {
      unsigned int cnt = ngt;
      for (int b = 255; b >= 0; --b) {
        unsigned int c = hist[b];
        if (cnt + c >= (unsigned)PRE) { sh_selB = (unsigned)b; sh_ngt = cnt; sh_binc = c; break; }
        cnt += c;
      }
    }
    __syncthreads();
    prefix |= (sh_selB << shift);
    prefMask |= (0xFFu << shift);
    ngt = sh_ngt;
    neq = sh_binc;
    __syncthreads();
  }
  const unsigned int T = prefix;
  const unsigned int needed = (unsigned)PRE - ngt;
  unsigned int J = 0xFFFFFFFFu;
  if (needed < neq) {
    if (t < 256) hist[t] = 0;
    __syncthreads();
    for (int i = t; i < KPER; i += 1024)
      if (ordf(sc[i]) == T) atomicAdd(&hist[i >> 7], 1u);
    __syncthreads();
    if (t == 0) {
      unsigned int cnt = 0;
      for (int b = 0; b < 256; ++b) {
        unsigned int c = hist[b];
        if (cnt + c >= needed) { sh_selB = (unsigned)b; sh_ngt = needed - cnt; break; }
        cnt += c;
      }
    }
    __syncthreads();
    const unsigned int selH = sh_selB;
    const unsigned int needLow = sh_ngt;
    __syncthreads();
    if (t < 128) hist[t] = 0;
    __syncthreads();
    for (int i = t; i < KPER; i += 1024)
      if (ordf(sc[i]) == T && ((unsigned)(i >> 7)) == selH) atomicAdd(&hist[i & 127], 1u);
    __syncthreads();
    if (t == 0) {
      unsigned int cnt = 0;
      for (int b = 0; b < 128; ++b) {
        unsigned int c = hist[b];
        if (cnt + c >= needLow) { sh_selB = (selH << 7) | (unsigned)b; break; }
        cnt += c;
      }
    }
    __syncthreads();
    J = sh_selB;
  }

  if (t == 0) { sh_num = 0; sh_m2 = 0ull; }
  __syncthreads();
  unsigned long long lm = 0ull;
  for (int i = t; i < KPER; i += 1024) {
    unsigned int u = ordf(sc[i]);
    unsigned long long key = (((unsigned long long)u) << 32) | (unsigned long long)(~(unsigned int)i);
    if (key > lm) lm = key;
    bool in = (u > T) || (u == T && (unsigned)i <= J);
    if (in) {
      unsigned int p = atomicAdd(&sh_num, 1u);
      cbox[(size_t)n * PRE + p] = boxes[(size_t)n * KPER + i];
      ckey[(size_t)n * PRE + p] = key;
    }
  }
#pragma unroll
  for (int off = 32; off; off >>= 1) {
    unsigned long long o = shfl_down_u64(lm, off);
    if (o > lm) lm = o;
  }
  if ((t & 63) == 0) atomicMax(&sh_m2, lm);
  __syncthreads();
  if (t == 0) m2out[n] = sh_m2;
}

// ---------------------------------------------------------------------------
// K4: exact sequential NMS, 300 picks, candidates register-resident.
// ---------------------------------------------------------------------------
__global__ __launch_bounds__(1024) void k_nms(const float4* __restrict__ cbox,
                                              const unsigned long long* __restrict__ ckey,
                                              const unsigned long long* __restrict__ m2arr,
                                              float* __restrict__ out) {
  const int n = blockIdx.x;
  const int t = threadIdx.x;
  __shared__ unsigned long long red[16];
  __shared__ unsigned long long pick_sh;
  __shared__ float4 pb_sh;

  float4 bx[6];
  unsigned long long ky[6];
  bool alive[6];
#pragma unroll
  for (int s = 0; s < 6; ++s) {
    int g = s * 1024 + t;
    if (g < PRE) {
      bx[s] = cbox[(size_t)n * PRE + g];
      ky[s] = ckey[(size_t)n * PRE + g];
      alive[s] = true;
    } else {
      bx[s] = make_float4(0.f, 0.f, 0.f, 0.f);
      ky[s] = 0ull;
      alive[s] = false;
    }
  }
  const unsigned long long M2 = m2arr[n];
  const int wid = t >> 6, lane = t & 63;

  for (int it = 0; it < POST; ++it) {
    unsigned long long lm = 0ull;
#pragma unroll
    for (int s = 0; s < 6; ++s)
      if (alive[s] && ky[s] > lm) lm = ky[s];
#pragma unroll
    for (int off = 32; off; off >>= 1) {
      unsigned long long o = shfl_down_u64(lm, off);
      if (o > lm) lm = o;
    }
    if (lane == 0) red[wid] = lm;
    __syncthreads();
    if (wid == 0) {
      unsigned long long m1 = (lane < 16) ? red[lane] : 0ull;
#pragma unroll
      for (int m = 8; m; m >>= 1) {
        unsigned long long o = shfl_xor_u64(m1, m);
        if (o > m1) m1 = o;
      }
      if (lane == 0)
        pick_sh = ((m1 >> 32) > 0x007FFFFFull) ? m1 : M2;
    }
    __syncthreads();
    const unsigned long long pick = pick_sh;
#pragma unroll
    for (int s = 0; s < 6; ++s) {
      if (ky[s] == pick) {
        pb_sh = bx[s];
        float4 b = bx[s];
        float* orow = out + ((size_t)n * POST + it) * 4;
        orow[0] = b.x; orow[1] = b.y; orow[2] = b.z; orow[3] = b.w;
        out[(size_t)NIMG * POST * 4 + (size_t)n * POST + it] = (float)n;
      }
    }
    __syncthreads();
    const float4 p = pb_sh;
    const float pa = __fmul_rn(__fsub_rn(p.z, p.x), __fsub_rn(p.w, p.y));
#pragma unroll
    for (int s = 0; s < 6; ++s) {
      if (!alive[s]) continue;
      float ltx = fmaxf(p.x, bx[s].x);
      float lty = fmaxf(p.y, bx[s].y);
      float rbx = fminf(p.z, bx[s].z);
      float rby = fminf(p.w, bx[s].w);
      float wv = fmaxf(__fsub_rn(rbx, ltx), 0.0f);
      float hv = fmaxf(__fsub_rn(rby, lty), 0.0f);
      float inter = __fmul_rn(wv, hv);
      float a2 = __fmul_rn(__fsub_rn(bx[s].z, bx[s].x), __fsub_rn(bx[s].w, bx[s].y));
      float denom = __fadd_rn(__fsub_rn(__fadd_rn(pa, a2), inter), 1e-9f);
      float iou = __fdiv_rn(inter, denom);
      if (iou >= 0.7f) alive[s] = false;
    }
  }
}

extern "C" void kernel_launch(void* const* d_in, const int* in_sizes, int n_in,
                              void* d_out, int out_size, void* d_ws, size_t ws_size,
                              hipStream_t stream) {
  const float* x    = (const float*)d_in[0];
  const float* w1   = (const float*)d_in[1];
  const float* b1   = (const float*)d_in[2];
  const float* wcls = (const float*)d_in[3];
  const float* bcls = (const float*)d_in[4];
  const float* wbb  = (const float*)d_in[5];
  const float* bbb  = (const float*)d_in[6];
  float* out = (float*)d_out;

  char* ws = (char*)d_ws;
  size_t off = 0;
  float* feat = (float*)(ws + off);               off += (size_t)NIMG * HW * CIN * 4;
  float* scores = (float*)(ws + off);             off += (size_t)NIMG * KPER * 4;
  float4* boxes = (float4*)(ws + off);            off += (size_t)NIMG * KPER * 16;
  float4* cbox = (float4*)(ws + off);             off += (size_t)NIMG * PRE * 16;
  unsigned long long* ckey = (unsigned long long*)(ws + off); off += (size_t)NIMG * PRE * 8;
  unsigned long long* m2 = (unsigned long long*)(ws + off);   off += 256;
  float* WHT2 = (float*)(ws + off);               off += (size_t)WHT_ELEMS * 4;
  float* bh   = (float*)(ws + off);               off += 256;
  unsigned short* xTh = (unsigned short*)(ws + off); off += XT_BYTES;
  unsigned short* xTl = (unsigned short*)(ws + off); off += XT_BYTES;
  unsigned short* wpk = (unsigned short*)(ws + off); off += WPK_ELEMS * 2;

  k_zerox<<<2048, 256, 0, stream>>>((float4*)xTh, (float4*)xTl);
  k_prepxT<<<1600, 256, 0, stream>>>((const float4*)x, xTh, xTl);
  k_prepwPk<<<2048, 256, 0, stream>>>(w1, wpk);
  k_preph<<<128, 256, 0, stream>>>(wcls, bcls, wbb, bbb, WHT2, bh);
  k_convmfma<<<dim3(200, 4, 1), 256, 0, stream>>>(xTh, xTl, wpk, b1, feat);
  k_head<<<(NIMG * HW) / 16, 256, 0, stream>>>(feat, WHT2, bh, scores, boxes);
  k_topk<<<NIMG, 1024, 0, stream>>>(scores, boxes, cbox, ckey, m2);
  k_nms<<<NIMG, 1024, 0, stream>>>(cbox, ckey, m2, out);
}

// Round 3
// 784.032 us; speedup vs baseline: 3.2474x; 1.5451x over previous
//
#include <hip/hip_runtime.h>
#include <math.h>

#define NIMG 8
#define CIN  512
#define HF   50
#define WF   64
#define HW   3200
#define NA   9
#define KPER 28800   /* HW*NA per image */
#define PRE  6000
#define POST 300

#define WHT_ELEMS  32768     /* 512*64 */

/* sorted-candidate padding: 94 words * 64 = 6016 rows */
#define NW    94             /* u64 words per mask row */
#define NCAP  6016           /* padded candidate count */

/* padded NHWC f16 input: rows 52 (row p holds x row p-1; p=0,51 zero),
   cols 66 (col w' holds x col w'-1; w'=0,65 zero), ci contiguous. */
#define XTROWS 52
#define XTCOLS 66
#define XT_ELEMS ((size_t)NIMG * XTROWS * XTCOLS * CIN)   /* 14,057,472 */
#define XT_BYTES (XT_ELEMS * 2)                            /* 28,114,944 */

/* packed weights: [sp2][cob4][tap9][ks16][4096 f16] in LDS-physical tile order */
#define WPK_ELEMS ((size_t)2 * 4 * 9 * 16 * 4096)          /* 4,718,592 */
#define WPK_HALF  (4 * 9 * 16 * 4096)                      /* 2,359,296 */

/* scaling: x' = x*2^8, w' = w*2^14; acc scale 2^22 undone in epilogue */
#define SCALE_X 256.0f
#define SCALE_W 16384.0f
#define INV_SCALE (1.0f / 4194304.0f)   /* 2^-22 */

typedef _Float16 f16x8 __attribute__((ext_vector_type(8)));
typedef float f32x4  __attribute__((ext_vector_type(4)));
typedef unsigned short u16x8 __attribute__((ext_vector_type(8)));
typedef unsigned long long u64;

// Base anchors (x1,y1,x2,y2) computed in double, rounded to f32 (matches np.float32 cast)
__constant__ float BASEA[9][4] = {
  {-82.509667991878083f, -37.254833995939042f,  98.509667991878083f,  53.254833995939042f},
  {-173.01933598375617f, -82.509667991878083f, 189.01933598375617f,   98.509667991878083f},
  {-354.03867196751233f, -173.01933598375617f, 370.03867196751233f,  189.01933598375617f},
  { -56.0f,  -56.0f,  72.0f,  72.0f},
  {-120.0f, -120.0f, 136.0f, 136.0f},
  {-248.0f, -248.0f, 264.0f, 264.0f},
  {-37.254833995939042f, -82.509667991878083f,  53.254833995939042f,  98.509667991878083f},
  {-82.509667991878083f, -173.01933598375617f,  98.509667991878083f, 189.01933598375617f},
  {-173.01933598375617f, -354.03867196751233f, 189.01933598375617f,  370.03867196751233f},
};

__device__ __forceinline__ unsigned int ordf(float f) {
  unsigned int u = __float_as_uint(f);
  return (u & 0x80000000u) ? ~u : (u | 0x80000000u);
}

__device__ __forceinline__ unsigned short f2h(float f) {
  union { _Float16 h; unsigned short u; } cv;
  cv.h = (_Float16)f;             /* v_cvt_f16_f32, RNE */
  return cv.u;
}
__device__ __forceinline__ float h2f(unsigned short u) {
  union { _Float16 h; unsigned short u; } cv;
  cv.u = u;
  return (float)cv.h;
}

// ---------------------------------------------------------------------------
// Prep 0: zero xTh/xTl entirely (halos stay zero; interior overwritten next).
// ---------------------------------------------------------------------------
__global__ __launch_bounds__(256) void k_zerox(float4* __restrict__ a,
                                               float4* __restrict__ b) {
  const int tot = (int)(XT_BYTES / 16);   /* 1,757,184 */
  const int stride = gridDim.x * 256;
  const float4 z = make_float4(0.f, 0.f, 0.f, 0.f);
  for (int i = blockIdx.x * 256 + threadIdx.x; i < tot; i += stride) {
    a[i] = z;
    b[i] = z;
  }
}

// ---------------------------------------------------------------------------
// Prep A: x NCHW f32 -> padded NHWC f16 hi/lo of x*2^8.  LDS-transposed,
// coalesced both sides.  block = (n*50 + hrow)*4 + cichunk.
// g = x*256 is exact (pow2); g - hi exact (Sterbenz); lo = f16(g - hi).
// ---------------------------------------------------------------------------
__global__ __launch_bounds__(256) void k_prepxT(const float4* __restrict__ x4,
                                                unsigned short* __restrict__ xh,
                                                unsigned short* __restrict__ xl) {
  __shared__ float tile[128][65];
  const int b = blockIdx.x;
  const int cic = b & 3;
  const int rest = b >> 2;
  const int hrow = rest % 50;
  const int n = rest / 50;
  const int t = threadIdx.x;
#pragma unroll
  for (int jj = 0; jj < 8; ++jj) {
    const int e = t + 256 * jj;              /* 0..2047 */
    const int row = e >> 4, c4 = e & 15;
    const float4 v = x4[(((size_t)(n * CIN + cic * 128 + row) * HF + hrow) << 4) + c4];
    tile[row][c4 * 4 + 0] = v.x;
    tile[row][c4 * 4 + 1] = v.y;
    tile[row][c4 * 4 + 2] = v.z;
    tile[row][c4 * 4 + 3] = v.w;
  }
  __syncthreads();
#pragma unroll
  for (int jj = 0; jj < 4; ++jj) {
    const int e = t + 256 * jj;              /* 0..1023 */
    const int w = e >> 4, c8 = e & 15;
    const size_t base = ((size_t)((n * XTROWS + (hrow + 1)) * XTCOLS) + (w + 1)) * CIN
                        + cic * 128 + c8 * 8;
    u16x8 hv, lv;
#pragma unroll
    for (int u = 0; u < 8; ++u) {
      const float g = tile[c8 * 8 + u][w] * SCALE_X;
      const unsigned short hh = f2h(g);
      hv[u] = (short)hh;
      lv[u] = (short)f2h(g - h2f(hh));
    }
    *reinterpret_cast<u16x8*>(xh + base) = hv;
    *reinterpret_cast<u16x8*>(xl + base) = lv;
  }
}

// ---------------------------------------------------------------------------
// Prep B: w1 [co][ci][3][3] f32 -> wpk [sp][cob][tap][ks][4096] f16 of w*2^14,
// where the 4096-elem tile is exactly the conv kernel's LDS-physical A-tile
// layout:
//   i = col*32 + slot'*8 + j ;  slot' = s ^ ((col>>1)&3) ;
//   k_local = s*8 + j ; ci = ks*32 + k_local ; co = cob*128 + col.
// ---------------------------------------------------------------------------
__global__ __launch_bounds__(256) void k_prepwPk(const float* __restrict__ w1,
                                                 unsigned short* __restrict__ wpk) {
  const int tot = (int)WPK_ELEMS;
  const int stride = gridDim.x * 256;
  for (int idx = blockIdx.x * 256 + threadIdx.x; idx < tot; idx += stride) {
    const int i = idx & 4095;
    int rest = idx >> 12;
    const int ks = rest & 15; rest >>= 4;
    const int tap = rest % 9; rest /= 9;
    const int cob = rest & 3;
    const int sp = rest >> 2;
    const int col = i >> 5;
    const int slotp = (i >> 3) & 3;
    const int j = i & 7;
    const int s = slotp ^ ((col >> 1) & 3);
    const int ci = ks * 32 + s * 8 + j;
    const int co = cob * 128 + col;
    const float g = w1[((size_t)co * CIN + ci) * 9 + tap] * SCALE_W;
    const unsigned short hh = f2h(g);
    wpk[idx] = sp ? f2h(g - h2f(hh)) : hh;
  }
}

// ---------------------------------------------------------------------------
// Prep C: head weights WHT2[c4][o64][4] + biases bh[64]. (validated r3)
// ---------------------------------------------------------------------------
__global__ __launch_bounds__(256) void k_preph(const float* __restrict__ wc,
                                               const float* __restrict__ bc,
                                               const float* __restrict__ wb,
                                               const float* __restrict__ bb,
                                               float* __restrict__ WHT2,
                                               float* __restrict__ bh) {
  const int TOT = WHT_ELEMS + 64;
  const int stride = gridDim.x * 256;
  for (int idx = blockIdx.x * 256 + threadIdx.x; idx < TOT; idx += stride) {
    if (idx < WHT_ELEMS) {
      int r = idx & 3;
      int o = (idx >> 2) & 63;
      int c = (idx >> 8) * 4 + r;
      float v = 0.0f;
      if (o < 18) v = wc[(size_t)o * CIN + c];
      else if (o < 54) v = wb[(size_t)(o - 18) * CIN + c];
      WHT2[idx] = v;
    } else {
      int o = idx - WHT_ELEMS;
      float v = 0.0f;
      if (o < 18) v = bc[o];
      else if (o < 54) v = bb[o - 18];
      bh[o] = v;
    }
  }
}

// ---------------------------------------------------------------------------
// K1: 3x3 conv 512->512 as implicit GEMM on MFMA, fp32-emulated via scaled-f16
// hi/lo split (Ah*Bh + Ah*Bl + Al*Bh).  Validated round 2.
// ---------------------------------------------------------------------------
#define GLDS(gp, lp) __builtin_amdgcn_global_load_lds( \
    (const __attribute__((address_space(1))) unsigned int*)(gp), \
    (__attribute__((address_space(3))) unsigned int*)(lp), 16, 0, 0)

__global__ __launch_bounds__(256, 2) void k_convmfma(
    const unsigned short* __restrict__ xh,
    const unsigned short* __restrict__ xl,
    const unsigned short* __restrict__ wpk,
    const float* __restrict__ b1,
    float* __restrict__ feat) {
  __shared__ unsigned short lds[2][4][4096];   /* 64 KiB: [buf][Ah,Al,Bh,Bl] */

  const int pb  = blockIdx.x;        /* 0..199 : n*25 + hb */
  const int cob = blockIdx.y;        /* 0..3   : 128-co block */
  const int n   = pb / 25;
  const int h0  = (pb - n * 25) * 2;
  const int t   = threadIdx.x;
  const int wid = t >> 6;
  const int l   = t & 63;
  const int wm  = wid >> 1;          /* wave M index (co) */
  const int wn  = wid & 1;           /* wave N index (pos row) */

  /* staging constants */
  const int colp = l >> 2;                               /* w within 16-col group */
  const int sB = (((l & 3) ^ ((l >> 3) & 3)) << 3);      /* swizzled k-slot elem off */
  const unsigned short* xsrc = (wid == 3) ? xl : xh;
  const size_t wA_base = (size_t)(wid & 1) * WPK_HALF;

  /* fragment-read constants */
  const int fr = l & 15;
  const int fq = l >> 4;
  const int slotr = ((fq ^ ((fr >> 1) & 3)) << 4);       /* swizzled 16B slot (bytes) */

  f32x4 acc[4][4] = {};

  auto stage = [&](int sbuf, int ti) {
    const int ks  = ti / 9;          /* ci chunk  (slow) */
    const int tap = ti - ks * 9;     /* 3x3 tap   (fast: L2 reuse of x rows) */
    if (wid < 2) {
      const unsigned short* gp = wpk + wA_base
          + ((size_t)((cob * 9 + tap) * 16 + ks) << 12) + l * 8;
      unsigned short* lp = &lds[sbuf][wid][0];
#pragma unroll
      for (int q = 0; q < 8; ++q)
        GLDS(gp + q * 512, lp + q * 512);
    } else {
      const int ky = (tap * 11) >> 5;       /* tap/3 for 0..8 */
      const int kx = tap - ky * 3;
      const size_t ebase = ((size_t)((n * XTROWS + h0 + ky) * XTCOLS + kx + colp) << 9)
                           + ks * 32 + sB;
      unsigned short* lp = &lds[sbuf][wid][0];
#pragma unroll
      for (int q = 0; q < 8; ++q)
        GLDS(xsrc + ebase + ((size_t)(((q >> 2) * XTCOLS + (q & 3) * 16)) << 9),
             lp + q * 512);
    }
  };

  stage(0, 0);
  __syncthreads();

  int buf = 0;
  for (int ti = 0; ti < 144; ++ti) {
    if (ti < 143) stage(buf ^ 1, ti + 1);   /* issue next-step loads first */

    f16x8 ah[4], al[4], bhf[4], blf[4];
#pragma unroll
    for (int mi = 0; mi < 4; ++mi) {
      const int off = (((wm << 6) + (mi << 4) + fr) << 6) + slotr;
      ah[mi] = *(const f16x8*)((const char*)&lds[buf][0][0] + off);
      al[mi] = *(const f16x8*)((const char*)&lds[buf][1][0] + off);
    }
#pragma unroll
    for (int ni = 0; ni < 4; ++ni) {
      const int off = (((wn << 6) + (ni << 4) + fr) << 6) + slotr;
      bhf[ni] = *(const f16x8*)((const char*)&lds[buf][2][0] + off);
      blf[ni] = *(const f16x8*)((const char*)&lds[buf][3][0] + off);
    }
#pragma unroll
    for (int mi = 0; mi < 4; ++mi)
#pragma unroll
      for (int ni = 0; ni < 4; ++ni) {
        acc[mi][ni] = __builtin_amdgcn_mfma_f32_16x16x32_f16(ah[mi], bhf[ni], acc[mi][ni], 0, 0, 0);
        acc[mi][ni] = __builtin_amdgcn_mfma_f32_16x16x32_f16(ah[mi], blf[ni], acc[mi][ni], 0, 0, 0);
        acc[mi][ni] = __builtin_amdgcn_mfma_f32_16x16x32_f16(al[mi], bhf[ni], acc[mi][ni], 0, 0, 0);
      }
    __syncthreads();                        /* drains vmcnt(0): next buf ready */
    buf ^= 1;
  }

  /* epilogue: rescale 2^-22 + bias + relu, float4 per lane into NHWC feat */
  const int h = h0 + wn;
#pragma unroll
  for (int mi = 0; mi < 4; ++mi) {
    const int co = (cob << 7) + (wm << 6) + (mi << 4) + (fq << 2);
    const float4 bias = *(const float4*)&b1[co];
#pragma unroll
    for (int ni = 0; ni < 4; ++ni) {
      const int w = (ni << 4) + fr;
      float4 v;
      v.x = fmaxf(fmaf(acc[mi][ni][0], INV_SCALE, bias.x), 0.0f);
      v.y = fmaxf(fmaf(acc[mi][ni][1], INV_SCALE, bias.y), 0.0f);
      v.z = fmaxf(fmaf(acc[mi][ni][2], INV_SCALE, bias.z), 0.0f);
      v.w = fmaxf(fmaf(acc[mi][ni][3], INV_SCALE, bias.w), 0.0f);
      *(float4*)(feat + (((size_t)n * HW + h * WF + w) << 9) + co) = v;
    }
  }
}

// ---------------------------------------------------------------------------
// K2: 1x1 heads + softmax-fg + box decode + clip + min-size filter.
// (identical numerics to validated r2 kernel)
// ---------------------------------------------------------------------------
__global__ __launch_bounds__(256) void k_head(const float* __restrict__ feat,
                                              const float* __restrict__ WHT2,
                                              const float* __restrict__ bh,
                                              float* __restrict__ scores,
                                              float4* __restrict__ boxes) {
  __shared__ float fsh[16][512];
  __shared__ float vsh[16][64];
  const int t = threadIdx.x;
  const int wvid = t >> 6;
  const int o = t & 63;
  const int pos0 = blockIdx.x * 16;

  for (int i = t; i < 16 * 512; i += 256)
    fsh[i >> 9][i & 511] = feat[((size_t)pos0 << 9) + i];
  __syncthreads();

  {
    const int p0 = wvid * 4;
    float a0 = 0.f, a1 = 0.f, a2 = 0.f, a3 = 0.f;
    const float4* wp = reinterpret_cast<const float4*>(WHT2);
    const float4* f0 = reinterpret_cast<const float4*>(&fsh[p0 + 0][0]);
    const float4* f1 = reinterpret_cast<const float4*>(&fsh[p0 + 1][0]);
    const float4* f2 = reinterpret_cast<const float4*>(&fsh[p0 + 2][0]);
    const float4* f3 = reinterpret_cast<const float4*>(&fsh[p0 + 3][0]);
#pragma unroll 4
    for (int c4 = 0; c4 < 128; ++c4) {
      float4 w4 = wp[c4 * 64 + o];
      float4 v;
      v = f0[c4];
      a0 = fmaf(w4.x, v.x, a0); a0 = fmaf(w4.y, v.y, a0);
      a0 = fmaf(w4.z, v.z, a0); a0 = fmaf(w4.w, v.w, a0);
      v = f1[c4];
      a1 = fmaf(w4.x, v.x, a1); a1 = fmaf(w4.y, v.y, a1);
      a1 = fmaf(w4.z, v.z, a1); a1 = fmaf(w4.w, v.w, a1);
      v = f2[c4];
      a2 = fmaf(w4.x, v.x, a2); a2 = fmaf(w4.y, v.y, a2);
      a2 = fmaf(w4.z, v.z, a2); a2 = fmaf(w4.w, v.w, a2);
      v = f3[c4];
      a3 = fmaf(w4.x, v.x, a3); a3 = fmaf(w4.y, v.y, a3);
      a3 = fmaf(w4.z, v.z, a3); a3 = fmaf(w4.w, v.w, a3);
    }
    float bv = bh[o];
    vsh[p0 + 0][o] = a0 + bv;
    vsh[p0 + 1][o] = a1 + bv;
    vsh[p0 + 2][o] = a2 + bv;
    vsh[p0 + 3][o] = a3 + bv;
  }
  __syncthreads();

  if (t < 144) {
    const int p2 = t / 9, a = t % 9;
    const int pos = pos0 + p2;
    const int n = pos / HW;
    const int r = pos - n * HW;
    const int ph = r >> 6;
    const int pw = r & 63;

    float l0 = vsh[p2][a * 2];
    float l1 = vsh[p2][a * 2 + 1];
    float m  = fmaxf(l0, l1);
    float e0 = (float)exp((double)__fsub_rn(l0, m));
    float e1 = (float)exp((double)__fsub_rn(l1, m));
    float fg = __fdiv_rn(e1, __fadd_rn(e0, e1));

    float d0 = vsh[p2][18 + a * 4 + 0];
    float d1 = vsh[p2][18 + a * 4 + 1];
    float d2 = vsh[p2][18 + a * 4 + 2];
    float d3 = vsh[p2][18 + a * 4 + 3];

    float sx = (float)(pw * 16);
    float sy = (float)(ph * 16);
    float ax1 = __fadd_rn(BASEA[a][0], sx);
    float ay1 = __fadd_rn(BASEA[a][1], sy);
    float ax2 = __fadd_rn(BASEA[a][2], sx);
    float ay2 = __fadd_rn(BASEA[a][3], sy);
    float aw = __fsub_rn(ax2, ax1);
    float ah = __fsub_rn(ay2, ay1);
    float acx = __fadd_rn(ax1, __fmul_rn(0.5f, aw));
    float acy = __fadd_rn(ay1, __fmul_rn(0.5f, ah));
    float cx = __fadd_rn(__fmul_rn(d0, aw), acx);
    float cy = __fadd_rn(__fmul_rn(d1, ah), acy);
    float pwd = __fmul_rn((float)exp((double)d2), aw);
    float phd = __fmul_rn((float)exp((double)d3), ah);
    float x1 = __fsub_rn(cx, __fmul_rn(0.5f, pwd));
    float y1 = __fsub_rn(cy, __fmul_rn(0.5f, phd));
    float x2 = __fadd_rn(cx, __fmul_rn(0.5f, pwd));
    float y2 = __fadd_rn(cy, __fmul_rn(0.5f, phd));
    x1 = fminf(fmaxf(x1, 0.0f), 1024.0f);
    x2 = fminf(fmaxf(x2, 0.0f), 1024.0f);
    y1 = fminf(fmaxf(y1, 0.0f), 800.0f);
    y2 = fminf(fmaxf(y2, 0.0f), 800.0f);
    float wsz = __fsub_rn(x2, x1);
    float hsz = __fsub_rn(y2, y1);
    float sc = (wsz >= 16.0f && hsz >= 16.0f) ? fg : -__builtin_huge_valf();

    const int idx = n * KPER + r * NA + a;
    scores[idx] = sc;
    boxes[idx] = make_float4(x1, y1, x2, y2);
  }
}

// ---------------------------------------------------------------------------
// K3: exact top-6000 per image via radix select (ties: lowest idx, matching
// lax.top_k stability); emits the 6000 keys (unordered compaction).
// key = ordf(score)<<32 | ~idx  (unique; desc-sort = top_k order).
// ---------------------------------------------------------------------------
__global__ __launch_bounds__(1024) void k_topk(const float* __restrict__ scores,
                                               u64* __restrict__ ckey) {
  const int n = blockIdx.x;
  const int t = threadIdx.x;
  __shared__ unsigned int hist[256];
  __shared__ unsigned int sh_selB, sh_ngt, sh_binc, sh_num;
  const float* sc = scores + (size_t)n * KPER;

  unsigned int prefix = 0, prefMask = 0, ngt = 0, neq = 0;
  for (int shift = 24; shift >= 0; shift -= 8) {
    if (t < 256) hist[t] = 0;
    __syncthreads();
    for (int i = t; i < KPER; i += 1024) {
      unsigned int u = ordf(sc[i]);
      if ((u & prefMask) == prefix) atomicAdd(&hist[(u >> shift) & 255], 1u);
    }
    __syncthreads();
    if (t == 0) {
      unsigned int cnt = ngt;
      for (int b = 255; b >= 0; --b) {
        unsigned int c = hist[b];
        if (cnt + c >= (unsigned)PRE) { sh_selB = (unsigned)b; sh_ngt = cnt; sh_binc = c; break; }
        cnt += c;
      }
    }
    __syncthreads();
    prefix |= (sh_selB << shift);
    prefMask |= (0xFFu << shift);
    ngt = sh_ngt;
    neq = sh_binc;
    __syncthreads();
  }
  const unsigned int T = prefix;
  const unsigned int needed = (unsigned)PRE - ngt;
  unsigned int J = 0xFFFFFFFFu;
  if (needed < neq) {
    if (t < 256) hist[t] = 0;
    __syncthreads();
    for (int i = t; i < KPER; i += 1024)
      if (ordf(sc[i]) == T) atomicAdd(&hist[i >> 7], 1u);
    __syncthreads();
    if (t == 0) {
      unsigned int cnt = 0;
      for (int b = 0; b < 256; ++b) {
        unsigned int c = hist[b];
        if (cnt + c >= needed) { sh_selB = (unsigned)b; sh_ngt = needed - cnt; break; }
        cnt += c;
      }
    }
    __syncthreads();
    const unsigned int selH = sh_selB;
    const unsigned int needLow = sh_ngt;
    __syncthreads();
    if (t < 128) hist[t] = 0;
    __syncthreads();
    for (int i = t; i < KPER; i += 1024)
      if (ordf(sc[i]) == T && ((unsigned)(i >> 7)) == selH) atomicAdd(&hist[i & 127], 1u);
    __syncthreads();
    if (t == 0) {
      unsigned int cnt = 0;
      for (int b = 0; b < 128; ++b) {
        unsigned int c = hist[b];
        if (cnt + c >= needLow) { sh_selB = (selH << 7) | (unsigned)b; break; }
        cnt += c;
      }
    }
    __syncthreads();
    J = sh_selB;
  }

  if (t == 0) sh_num = 0;
  __syncthreads();
  for (int i = t; i < KPER; i += 1024) {
    unsigned int u = ordf(sc[i]);
    bool in = (u > T) || (u == T && (unsigned)i <= J);
    if (in) {
      unsigned int p = atomicAdd(&sh_num, 1u);
      ckey[(size_t)n * PRE + p] = (((u64)u) << 32) | (u64)(~(unsigned int)i);
    }
  }
}

// ---------------------------------------------------------------------------
// K4a: per-image bitonic sort (descending) of the 6000 keys in LDS (pad 8192
// with 0).  Desc key order == lax.top_k order (score desc, idx asc).
// Outputs: sbox[n][6016] gathered sorted boxes (pad zeros),
//          valid[n][128] bitmap of score > -inf.
// ---------------------------------------------------------------------------
__global__ __launch_bounds__(1024) void k_sortc(const u64* __restrict__ ckey,
                                                const float4* __restrict__ boxes,
                                                float4* __restrict__ sbox,
                                                u64* __restrict__ valid) {
  __shared__ u64 sk[8192];
  const int n = blockIdx.x;
  const int t = threadIdx.x;
  for (int e = t; e < 8192; e += 1024)
    sk[e] = (e < PRE) ? ckey[(size_t)n * PRE + e] : 0ull;
  __syncthreads();
  for (int k = 2; k <= 8192; k <<= 1) {
    for (int j = k >> 1; j > 0; j >>= 1) {
      for (int p = t; p < 4096; p += 1024) {
        const int i = ((p & ~(j - 1)) << 1) | (p & (j - 1));
        const int ip = i | j;
        u64 a = sk[i], b = sk[ip];
        const bool desc = ((i & k) == 0);
        if ((a < b) == desc) { sk[i] = b; sk[ip] = a; }
      }
      __syncthreads();
    }
  }
  for (int e = t; e < NCAP; e += 1024) {
    float4 bx = make_float4(0.f, 0.f, 0.f, 0.f);
    if (e < PRE) {
      unsigned idx = ~(unsigned)(sk[e] & 0xFFFFFFFFull);
      bx = boxes[(size_t)n * KPER + idx];
    }
    sbox[(size_t)n * NCAP + e] = bx;
  }
  if (t < 128) {
    u64 w = 0;
    if (t < NW) {
      for (int b = 0; b < 64; ++b) {
        int e = t * 64 + b;
        if (e < PRE && ((sk[e] >> 32) > 0x007FFFFFull)) w |= 1ull << b;
      }
    }
    valid[n * 128 + t] = w;
  }
}

// ---------------------------------------------------------------------------
// K4b: IoU>=0.7 bitmask.  mask[n][i][jb] bit b = IoU(sorted i, sorted jb*64+b).
// Only jb >= ib computed; jb < ib zero-filled (scan never needs them).
// IoU arithmetic op-for-op identical to the validated sequential k_nms.
// ---------------------------------------------------------------------------
__global__ __launch_bounds__(64) void k_mask(const float4* __restrict__ sbox,
                                             u64* __restrict__ mask) {
  const int ib = blockIdx.x;
  const int jb = blockIdx.y;
  const int n  = blockIdx.z;
  const int r  = threadIdx.x;
  const int i  = ib * 64 + r;
  u64* mout = mask + ((size_t)(n * NCAP) + i) * NW + jb;
  if (jb < ib) { *mout = 0ull; return; }
  __shared__ float4 jbox[64];
  jbox[r] = sbox[(size_t)n * NCAP + jb * 64 + r];
  __syncthreads();
  const float4 p = sbox[(size_t)n * NCAP + i];
  const float pa = __fmul_rn(__fsub_rn(p.z, p.x), __fsub_rn(p.w, p.y));
  u64 word = 0;
#pragma unroll 8
  for (int b = 0; b < 64; ++b) {
    const float4 q = jbox[b];
    float ltx = fmaxf(p.x, q.x);
    float lty = fmaxf(p.y, q.y);
    float rbx = fminf(p.z, q.z);
    float rby = fminf(p.w, q.w);
    float wv = fmaxf(__fsub_rn(rbx, ltx), 0.0f);
    float hv = fmaxf(__fsub_rn(rby, lty), 0.0f);
    float inter = __fmul_rn(wv, hv);
    float a2 = __fmul_rn(__fsub_rn(q.z, q.x), __fsub_rn(q.w, q.y));
    float denom = __fadd_rn(__fsub_rn(__fadd_rn(pa, a2), inter), 1e-9f);
    float iou = __fdiv_rn(inter, denom);
    if (iou >= 0.7f) word |= (1ull << b);
  }
  *mout = word;
}

// ---------------------------------------------------------------------------
// K4c: bit-scan.  One wave per image; suppressed set = 94 u64 words held as
// s0/s1 per lane (lane l owns words 2l, 2l+1).  Walk candidates in sorted
// order; keep iff valid & ~suppressed (== reference argmax sequence); on keep
// OR row i of mask.  Rows group-of-8 prefetched (dwordx4/lane) to hide L2
// latency.  If <300 keeps after 6000, pad with sorted candidate 0 (exactly
// the reference's all--inf argmax=0 behavior).
// ---------------------------------------------------------------------------
__global__ __launch_bounds__(64) void k_scan(const u64* __restrict__ mask,
                                             const u64* __restrict__ valid,
                                             const float4* __restrict__ sbox,
                                             float* __restrict__ out) {
  const int n = blockIdx.x;
  const int lane = threadIdx.x;
  u64 s0 = 0, s1 = 0;
  const u64 v0 = valid[n * 128 + 2 * lane];
  const u64 v1 = valid[n * 128 + 2 * lane + 1];
  const u64* mrow = mask + (size_t)n * NCAP * NW;
  __shared__ int keep_list[POST];
  int kept = 0;

  ulonglong2 cur[8], nxt[8];
#pragma unroll
  for (int r = 0; r < 8; ++r)
    cur[r] = ((const ulonglong2*)(mrow + (size_t)r * NW))[lane];

  for (int g = 0; g < PRE / 8; ++g) {
    if (kept >= POST) break;
    if (g < PRE / 8 - 1) {
#pragma unroll
      for (int r = 0; r < 8; ++r)
        nxt[r] = ((const ulonglong2*)(mrow + (size_t)((g + 1) * 8 + r) * NW))[lane];
    }
#pragma unroll
    for (int r = 0; r < 8; ++r) {
      if (kept < POST) {
        const int i = g * 8 + r;
        const int w = i >> 6;
        const u64 avail = (w & 1) ? (v1 & ~s1) : (v0 & ~s0);
        const unsigned h32 = (unsigned)(avail >> (i & 32));
        const unsigned wrd = __shfl(h32, w >> 1, 64);
        if ((wrd >> (i & 31)) & 1u) {
          if (lane == 0) keep_list[kept] = i;
          ++kept;
          s0 |= cur[r].x;
          s1 |= cur[r].y;
        }
      }
    }
#pragma unroll
    for (int r = 0; r < 8; ++r) cur[r] = nxt[r];
  }
  __syncthreads();

  for (int it = lane; it < POST; it += 64) {
    const int cand = (it < kept) ? keep_list[it] : 0;
    const float4 b = sbox[(size_t)n * NCAP + cand];
    float* orow = out + ((size_t)n * POST + it) * 4;
    orow[0] = b.x; orow[1] = b.y; orow[2] = b.z; orow[3] = b.w;
    out[(size_t)NIMG * POST * 4 + (size_t)n * POST + it] = (float)n;
  }
}

extern "C" void kernel_launch(void* const* d_in, const int* in_sizes, int n_in,
                              void* d_out, int out_size, void* d_ws, size_t ws_size,
                              hipStream_t stream) {
  const float* x    = (const float*)d_in[0];
  const float* w1   = (const float*)d_in[1];
  const float* b1   = (const float*)d_in[2];
  const float* wcls = (const float*)d_in[3];
  const float* bcls = (const float*)d_in[4];
  const float* wbb  = (const float*)d_in[5];
  const float* bbb  = (const float*)d_in[6];
  float* out = (float*)d_out;

  char* ws = (char*)d_ws;
  size_t off = 0;
  float* feat = (float*)(ws + off);               off += (size_t)NIMG * HW * CIN * 4;
  float* scores = (float*)(ws + off);             off += (size_t)NIMG * KPER * 4;
  float4* boxes = (float4*)(ws + off);            off += (size_t)NIMG * KPER * 16;
  u64* ckey = (u64*)(ws + off);                   off += (size_t)NIMG * PRE * 8;
  float4* sbox = (float4*)(ws + off);             off += (size_t)NIMG * NCAP * 16;
  u64* valid = (u64*)(ws + off);                  off += (size_t)NIMG * 128 * 8;
  u64* mask = (u64*)(ws + off);                   off += (size_t)NIMG * NCAP * NW * 8;
  float* WHT2 = (float*)(ws + off);               off += (size_t)WHT_ELEMS * 4;
  float* bh   = (float*)(ws + off);               off += 256;
  unsigned short* xTh = (unsigned short*)(ws + off); off += XT_BYTES;
  unsigned short* xTl = (unsigned short*)(ws + off); off += XT_BYTES;
  unsigned short* wpk = (unsigned short*)(ws + off); off += WPK_ELEMS * 2;

  k_zerox<<<2048, 256, 0, stream>>>((float4*)xTh, (float4*)xTl);
  k_prepxT<<<1600, 256, 0, stream>>>((const float4*)x, xTh, xTl);
  k_prepwPk<<<2048, 256, 0, stream>>>(w1, wpk);
  k_preph<<<128, 256, 0, stream>>>(wcls, bcls, wbb, bbb, WHT2, bh);
  k_convmfma<<<dim3(200, 4, 1), 256, 0, stream>>>(xTh, xTl, wpk, b1, feat);
  k_head<<<(NIMG * HW) / 16, 256, 0, stream>>>(feat, WHT2, bh, scores, boxes);
  k_topk<<<NIMG, 1024, 0, stream>>>(scores, ckey);
  k_sortc<<<NIMG, 1024, 0, stream>>>(ckey, boxes, sbox, valid);
  k_mask<<<dim3(NW, NW, NIMG), 64, 0, stream>>>(sbox, mask);
  k_scan<<<NIMG, 64, 0, stream>>>(mask, valid, sbox, out);
}

// Round 4
// 756.624 us; speedup vs baseline: 3.3650x; 1.0362x over previous
//
#include <hip/hip_runtime.h>
#include <math.h>

#define NIMG 8
#define CIN  512
#define HF   50
#define WF   64
#define HW   3200
#define NA   9
#define KPER 28800   /* HW*NA per image */
#define PRE  6000
#define POST 300

#define WHT_ELEMS  32768     /* 512*64 */

/* sorted-candidate padding: 94 words * 64 = 6016 rows */
#define NW    94             /* u64 words per mask row */
#define NCAP  6016           /* padded candidate count */
#define NTRI  4465           /* NW*(NW+1)/2 upper-tri blocks */

/* padded NHWC f16 input: rows 52 (row p holds x row p-1; p=0,51 zero),
   cols 66 (col w' holds x col w'-1; w'=0,65 zero), ci contiguous. */
#define XTROWS 52
#define XTCOLS 66
#define XT_ELEMS ((size_t)NIMG * XTROWS * XTCOLS * CIN)   /* 14,057,472 */
#define XT_BYTES (XT_ELEMS * 2)                            /* 28,114,944 */

/* packed weights: [sp2][cob4][tap9][ks16][4096 f16] in LDS-physical tile order */
#define WPK_ELEMS ((size_t)2 * 4 * 9 * 16 * 4096)          /* 4,718,592 */
#define WPK_HALF  (4 * 9 * 16 * 4096)                      /* 2,359,296 */

/* scaling: x' = x*2^8, w' = w*2^14; acc scale 2^22 undone in epilogue */
#define SCALE_X 256.0f
#define SCALE_W 16384.0f
#define INV_SCALE (1.0f / 4194304.0f)   /* 2^-22 */

/* prep_all block ranges */
#define PB_XT   1600
#define PB_HALO 64
#define PB_WPK  288
#define PB_PH   16
#define PB_TOT  (PB_XT + PB_HALO + PB_WPK + PB_PH)   /* 1968 */

/* halo vec8 counts */
#define HALO_VPI 14848        /* vec8 per image per array */
#define HALO_TOT (NIMG * HALO_VPI)   /* 118,784 */

typedef _Float16 f16x8 __attribute__((ext_vector_type(8)));
typedef float f32x4  __attribute__((ext_vector_type(4)));
typedef unsigned short u16x8 __attribute__((ext_vector_type(8)));
typedef unsigned long long u64;

// Base anchors (x1,y1,x2,y2) computed in double, rounded to f32 (matches np.float32 cast)
__constant__ float BASEA[9][4] = {
  {-82.509667991878083f, -37.254833995939042f,  98.509667991878083f,  53.254833995939042f},
  {-173.01933598375617f, -82.509667991878083f, 189.01933598375617f,   98.509667991878083f},
  {-354.03867196751233f, -173.01933598375617f, 370.03867196751233f,  189.01933598375617f},
  { -56.0f,  -56.0f,  72.0f,  72.0f},
  {-120.0f, -120.0f, 136.0f, 136.0f},
  {-248.0f, -248.0f, 264.0f, 264.0f},
  {-37.254833995939042f, -82.509667991878083f,  53.254833995939042f,  98.509667991878083f},
  {-82.509667991878083f, -173.01933598375617f,  98.509667991878083f, 189.01933598375617f},
  {-173.01933598375617f, -354.03867196751233f, 189.01933598375617f,  370.03867196751233f},
};

__device__ __forceinline__ unsigned int ordf(float f) {
  unsigned int u = __float_as_uint(f);
  return (u & 0x80000000u) ? ~u : (u | 0x80000000u);
}

__device__ __forceinline__ unsigned short f2h(float f) {
  union { _Float16 h; unsigned short u; } cv;
  cv.h = (_Float16)f;             /* v_cvt_f16_f32, RNE */
  return cv.u;
}
__device__ __forceinline__ float h2f(unsigned short u) {
  union { _Float16 h; unsigned short u; } cv;
  cv.u = u;
  return (float)cv.h;
}

// ---------------------------------------------------------------------------
// P: fused prep.  Blocks [0,1600): x NCHW f32 -> padded NHWC f16 hi/lo of
// x*2^8 (LDS-transposed; interior rows 1..50, cols 1..64).  [1600,1664):
// zero halo (rows {0,51} all cols; rows 1..50 cols {0,65}) -- exact
// complement of interior.  [1664,1952): weight pack (grid-stride).
// [1952,1968): head weight pack.
// ---------------------------------------------------------------------------
__global__ __launch_bounds__(256) void k_prep_all(
    const float4* __restrict__ x4,
    const float* __restrict__ w1,
    const float* __restrict__ wc, const float* __restrict__ bc,
    const float* __restrict__ wb, const float* __restrict__ bb,
    unsigned short* __restrict__ xh, unsigned short* __restrict__ xl,
    unsigned short* __restrict__ wpk,
    float* __restrict__ WHT2, float* __restrict__ bh) {
  __shared__ float tile[128][65];
  const int blk = blockIdx.x;
  const int t = threadIdx.x;

  if (blk < PB_XT) {
    /* --- x transpose + hi/lo split (validated r2) --- */
    const int cic = blk & 3;
    const int rest = blk >> 2;
    const int hrow = rest % 50;
    const int n = rest / 50;
#pragma unroll
    for (int jj = 0; jj < 8; ++jj) {
      const int e = t + 256 * jj;              /* 0..2047 */
      const int row = e >> 4, c4 = e & 15;
      const float4 v = x4[(((size_t)(n * CIN + cic * 128 + row) * HF + hrow) << 4) + c4];
      tile[row][c4 * 4 + 0] = v.x;
      tile[row][c4 * 4 + 1] = v.y;
      tile[row][c4 * 4 + 2] = v.z;
      tile[row][c4 * 4 + 3] = v.w;
    }
    __syncthreads();
#pragma unroll
    for (int jj = 0; jj < 4; ++jj) {
      const int e = t + 256 * jj;              /* 0..1023 */
      const int w = e >> 4, c8 = e & 15;
      const size_t base = ((size_t)((n * XTROWS + (hrow + 1)) * XTCOLS) + (w + 1)) * CIN
                          + cic * 128 + c8 * 8;
      u16x8 hv, lv;
#pragma unroll
      for (int u = 0; u < 8; ++u) {
        const float g = tile[c8 * 8 + u][w] * SCALE_X;
        const unsigned short hh = f2h(g);
        hv[u] = (short)hh;
        lv[u] = (short)f2h(g - h2f(hh));
      }
      *reinterpret_cast<u16x8*>(xh + base) = hv;
      *reinterpret_cast<u16x8*>(xl + base) = lv;
    }
  } else if (blk < PB_XT + PB_HALO) {
    /* --- halo zero --- */
    const u16x8 z = {0, 0, 0, 0, 0, 0, 0, 0};
    const int tid = (blk - PB_XT) * 256 + t;   /* 0..16383 */
    for (int v = tid; v < HALO_TOT; v += PB_HALO * 256) {
      const int n = v / HALO_VPI;
      const int r = v - n * HALO_VPI;
      int row, col, v8;
      if (r < 8448) {                       /* rows 0,51 : 2*66*64 */
        row = (r < 4224) ? 0 : 51;
        const int r2 = (r < 4224) ? r : r - 4224;
        col = r2 >> 6;
        v8 = r2 & 63;
      } else {                              /* rows 1..50, cols 0/65 */
        const int q = r - 8448;             /* 0..6399 */
        row = 1 + (q >> 7);
        const int rr = q & 127;
        col = (rr >= 64) ? 65 : 0;
        v8 = rr & 63;
      }
      const size_t off = ((size_t)((n * XTROWS + row) * XTCOLS) + col) * CIN + v8 * 8;
      *reinterpret_cast<u16x8*>(xh + off) = z;
      *reinterpret_cast<u16x8*>(xl + off) = z;
    }
  } else if (blk < PB_XT + PB_HALO + PB_WPK) {
    /* --- conv weight pack (validated r2) --- */
    const int tot = (int)WPK_ELEMS;
    const int tid = (blk - PB_XT - PB_HALO) * 256 + t;
    for (int idx = tid; idx < tot; idx += PB_WPK * 256) {
      const int i = idx & 4095;
      int rest = idx >> 12;
      const int ks = rest & 15; rest >>= 4;
      const int tap = rest % 9; rest /= 9;
      const int cob = rest & 3;
      const int sp = rest >> 2;
      const int col = i >> 5;
      const int slotp = (i >> 3) & 3;
      const int j = i & 7;
      const int s = slotp ^ ((col >> 1) & 3);
      const int ci = ks * 32 + s * 8 + j;
      const int co = cob * 128 + col;
      const float g = w1[((size_t)co * CIN + ci) * 9 + tap] * SCALE_W;
      const unsigned short hh = f2h(g);
      wpk[idx] = sp ? f2h(g - h2f(hh)) : hh;
    }
  } else {
    /* --- head weight pack (validated r3) --- */
    const int TOT = WHT_ELEMS + 64;
    const int tid = (blk - PB_XT - PB_HALO - PB_WPK) * 256 + t;
    for (int idx = tid; idx < TOT; idx += PB_PH * 256) {
      if (idx < WHT_ELEMS) {
        int r = idx & 3;
        int o = (idx >> 2) & 63;
        int c = (idx >> 8) * 4 + r;
        float v = 0.0f;
        if (o < 18) v = wc[(size_t)o * CIN + c];
        else if (o < 54) v = wb[(size_t)(o - 18) * CIN + c];
        WHT2[idx] = v;
      } else {
        int o = idx - WHT_ELEMS;
        float v = 0.0f;
        if (o < 18) v = bc[o];
        else if (o < 54) v = bb[o - 18];
        bh[o] = v;
      }
    }
  }
}

// ---------------------------------------------------------------------------
// K1: 3x3 conv 512->512 as implicit GEMM on MFMA, fp32-emulated via scaled-f16
// hi/lo split (Ah*Bh + Ah*Bl + Al*Bh).  Validated round 2.
// NEW (r4): XCD-aware block swizzle -- each XCD gets one cob + 100 contiguous
// pb blocks, so its weight working set (2.36 MB) is L2-resident.
// ---------------------------------------------------------------------------
#define GLDS(gp, lp) __builtin_amdgcn_global_load_lds( \
    (const __attribute__((address_space(1))) unsigned int*)(gp), \
    (__attribute__((address_space(3))) unsigned int*)(lp), 16, 0, 0)

__global__ __launch_bounds__(256, 2) void k_convmfma(
    const unsigned short* __restrict__ xh,
    const unsigned short* __restrict__ xl,
    const unsigned short* __restrict__ wpk,
    const float* __restrict__ b1,
    float* __restrict__ feat) {
  __shared__ unsigned short lds[2][4][4096];   /* 64 KiB: [buf][Ah,Al,Bh,Bl] */

  /* XCD swizzle: consecutive blockIdx round-robin XCDs (id%8).  xcd k ->
     cob = k>>1, pb chunk = (k&1)*100 + (id>>3).  Bijective over 800. */
  const int raw = blockIdx.x;
  const int xcd = raw & 7;
  const int idx = raw >> 3;          /* 0..99 */
  const int cob = xcd >> 1;          /* 0..3 */
  const int pb  = (xcd & 1) * 100 + idx;   /* 0..199 : n*25 + hb */

  const int n   = pb / 25;
  const int h0  = (pb - n * 25) * 2;
  const int t   = threadIdx.x;
  const int wid = t >> 6;
  const int l   = t & 63;
  const int wm  = wid >> 1;          /* wave M index (co) */
  const int wn  = wid & 1;           /* wave N index (pos row) */

  /* staging constants */
  const int colp = l >> 2;                               /* w within 16-col group */
  const int sB = (((l & 3) ^ ((l >> 3) & 3)) << 3);      /* swizzled k-slot elem off */
  const unsigned short* xsrc = (wid == 3) ? xl : xh;
  const size_t wA_base = (size_t)(wid & 1) * WPK_HALF;

  /* fragment-read constants */
  const int fr = l & 15;
  const int fq = l >> 4;
  const int slotr = ((fq ^ ((fr >> 1) & 3)) << 4);       /* swizzled 16B slot (bytes) */

  f32x4 acc[4][4] = {};

  auto stage = [&](int sbuf, int ti) {
    const int ks  = ti / 9;          /* ci chunk  (slow) */
    const int tap = ti - ks * 9;     /* 3x3 tap   (fast: L2 reuse of x rows) */
    if (wid < 2) {
      const unsigned short* gp = wpk + wA_base
          + ((size_t)((cob * 9 + tap) * 16 + ks) << 12) + l * 8;
      unsigned short* lp = &lds[sbuf][wid][0];
#pragma unroll
      for (int q = 0; q < 8; ++q)
        GLDS(gp + q * 512, lp + q * 512);
    } else {
      const int ky = (tap * 11) >> 5;       /* tap/3 for 0..8 */
      const int kx = tap - ky * 3;
      const size_t ebase = ((size_t)((n * XTROWS + h0 + ky) * XTCOLS + kx + colp) << 9)
                           + ks * 32 + sB;
      unsigned short* lp = &lds[sbuf][wid][0];
#pragma unroll
      for (int q = 0; q < 8; ++q)
        GLDS(xsrc + ebase + ((size_t)(((q >> 2) * XTCOLS + (q & 3) * 16)) << 9),
             lp + q * 512);
    }
  };

  stage(0, 0);
  __syncthreads();

  int buf = 0;
  for (int ti = 0; ti < 144; ++ti) {
    if (ti < 143) stage(buf ^ 1, ti + 1);   /* issue next-step loads first */

    f16x8 ah[4], al[4], bhf[4], blf[4];
#pragma unroll
    for (int mi = 0; mi < 4; ++mi) {
      const int off = (((wm << 6) + (mi << 4) + fr) << 6) + slotr;
      ah[mi] = *(const f16x8*)((const char*)&lds[buf][0][0] + off);
      al[mi] = *(const f16x8*)((const char*)&lds[buf][1][0] + off);
    }
#pragma unroll
    for (int ni = 0; ni < 4; ++ni) {
      const int off = (((wn << 6) + (ni << 4) + fr) << 6) + slotr;
      bhf[ni] = *(const f16x8*)((const char*)&lds[buf][2][0] + off);
      blf[ni] = *(const f16x8*)((const char*)&lds[buf][3][0] + off);
    }
#pragma unroll
    for (int mi = 0; mi < 4; ++mi)
#pragma unroll
      for (int ni = 0; ni < 4; ++ni) {
        acc[mi][ni] = __builtin_amdgcn_mfma_f32_16x16x32_f16(ah[mi], bhf[ni], acc[mi][ni], 0, 0, 0);
        acc[mi][ni] = __builtin_amdgcn_mfma_f32_16x16x32_f16(ah[mi], blf[ni], acc[mi][ni], 0, 0, 0);
        acc[mi][ni] = __builtin_amdgcn_mfma_f32_16x16x32_f16(al[mi], bhf[ni], acc[mi][ni], 0, 0, 0);
      }
    __syncthreads();                        /* drains vmcnt(0): next buf ready */
    buf ^= 1;
  }

  /* epilogue: rescale 2^-22 + bias + relu, float4 per lane into NHWC feat */
  const int h = h0 + wn;
#pragma unroll
  for (int mi = 0; mi < 4; ++mi) {
    const int co = (cob << 7) + (wm << 6) + (mi << 4) + (fq << 2);
    const float4 bias = *(const float4*)&b1[co];
#pragma unroll
    for (int ni = 0; ni < 4; ++ni) {
      const int w = (ni << 4) + fr;
      float4 v;
      v.x = fmaxf(fmaf(acc[mi][ni][0], INV_SCALE, bias.x), 0.0f);
      v.y = fmaxf(fmaf(acc[mi][ni][1], INV_SCALE, bias.y), 0.0f);
      v.z = fmaxf(fmaf(acc[mi][ni][2], INV_SCALE, bias.z), 0.0f);
      v.w = fmaxf(fmaf(acc[mi][ni][3], INV_SCALE, bias.w), 0.0f);
      *(float4*)(feat + (((size_t)n * HW + h * WF + w) << 9) + co) = v;
    }
  }
}

// ---------------------------------------------------------------------------
// K2: 1x1 heads + softmax-fg + box decode + clip + min-size filter.
// (identical numerics to validated r2 kernel)
// ---------------------------------------------------------------------------
__global__ __launch_bounds__(256) void k_head(const float* __restrict__ feat,
                                              const float* __restrict__ WHT2,
                                              const float* __restrict__ bh,
                                              float* __restrict__ scores,
                                              float4* __restrict__ boxes) {
  __shared__ float fsh[16][512];
  __shared__ float vsh[16][64];
  const int t = threadIdx.x;
  const int wvid = t >> 6;
  const int o = t & 63;
  const int pos0 = blockIdx.x * 16;

  for (int i = t; i < 16 * 512; i += 256)
    fsh[i >> 9][i & 511] = feat[((size_t)pos0 << 9) + i];
  __syncthreads();

  {
    const int p0 = wvid * 4;
    float a0 = 0.f, a1 = 0.f, a2 = 0.f, a3 = 0.f;
    const float4* wp = reinterpret_cast<const float4*>(WHT2);
    const float4* f0 = reinterpret_cast<const float4*>(&fsh[p0 + 0][0]);
    const float4* f1 = reinterpret_cast<const float4*>(&fsh[p0 + 1][0]);
    const float4* f2 = reinterpret_cast<const float4*>(&fsh[p0 + 2][0]);
    const float4* f3 = reinterpret_cast<const float4*>(&fsh[p0 + 3][0]);
#pragma unroll 4
    for (int c4 = 0; c4 < 128; ++c4) {
      float4 w4 = wp[c4 * 64 + o];
      float4 v;
      v = f0[c4];
      a0 = fmaf(w4.x, v.x, a0); a0 = fmaf(w4.y, v.y, a0);
      a0 = fmaf(w4.z, v.z, a0); a0 = fmaf(w4.w, v.w, a0);
      v = f1[c4];
      a1 = fmaf(w4.x, v.x, a1); a1 = fmaf(w4.y, v.y, a1);
      a1 = fmaf(w4.z, v.z, a1); a1 = fmaf(w4.w, v.w, a1);
      v = f2[c4];
      a2 = fmaf(w4.x, v.x, a2); a2 = fmaf(w4.y, v.y, a2);
      a2 = fmaf(w4.z, v.z, a2); a2 = fmaf(w4.w, v.w, a2);
      v = f3[c4];
      a3 = fmaf(w4.x, v.x, a3); a3 = fmaf(w4.y, v.y, a3);
      a3 = fmaf(w4.z, v.z, a3); a3 = fmaf(w4.w, v.w, a3);
    }
    float bv = bh[o];
    vsh[p0 + 0][o] = a0 + bv;
    vsh[p0 + 1][o] = a1 + bv;
    vsh[p0 + 2][o] = a2 + bv;
    vsh[p0 + 3][o] = a3 + bv;
  }
  __syncthreads();

  if (t < 144) {
    const int p2 = t / 9, a = t % 9;
    const int pos = pos0 + p2;
    const int n = pos / HW;
    const int r = pos - n * HW;
    const int ph = r >> 6;
    const int pw = r & 63;

    float l0 = vsh[p2][a * 2];
    float l1 = vsh[p2][a * 2 + 1];
    float m  = fmaxf(l0, l1);
    float e0 = (float)exp((double)__fsub_rn(l0, m));
    float e1 = (float)exp((double)__fsub_rn(l1, m));
    float fg = __fdiv_rn(e1, __fadd_rn(e0, e1));

    float d0 = vsh[p2][18 + a * 4 + 0];
    float d1 = vsh[p2][18 + a * 4 + 1];
    float d2 = vsh[p2][18 + a * 4 + 2];
    float d3 = vsh[p2][18 + a * 4 + 3];

    float sx = (float)(pw * 16);
    float sy = (float)(ph * 16);
    float ax1 = __fadd_rn(BASEA[a][0], sx);
    float ay1 = __fadd_rn(BASEA[a][1], sy);
    float ax2 = __fadd_rn(BASEA[a][2], sx);
    float ay2 = __fadd_rn(BASEA[a][3], sy);
    float aw = __fsub_rn(ax2, ax1);
    float ah = __fsub_rn(ay2, ay1);
    float acx = __fadd_rn(ax1, __fmul_rn(0.5f, aw));
    float acy = __fadd_rn(ay1, __fmul_rn(0.5f, ah));
    float cx = __fadd_rn(__fmul_rn(d0, aw), acx);
    float cy = __fadd_rn(__fmul_rn(d1, ah), acy);
    float pwd = __fmul_rn((float)exp((double)d2), aw);
    float phd = __fmul_rn((float)exp((double)d3), ah);
    float x1 = __fsub_rn(cx, __fmul_rn(0.5f, pwd));
    float y1 = __fsub_rn(cy, __fmul_rn(0.5f, phd));
    float x2 = __fadd_rn(cx, __fmul_rn(0.5f, pwd));
    float y2 = __fadd_rn(cy, __fmul_rn(0.5f, phd));
    x1 = fminf(fmaxf(x1, 0.0f), 1024.0f);
    x2 = fminf(fmaxf(x2, 0.0f), 1024.0f);
    y1 = fminf(fmaxf(y1, 0.0f), 800.0f);
    y2 = fminf(fmaxf(y2, 0.0f), 800.0f);
    float wsz = __fsub_rn(x2, x1);
    float hsz = __fsub_rn(y2, y1);
    float sc = (wsz >= 16.0f && hsz >= 16.0f) ? fg : -__builtin_huge_valf();

    const int idx = n * KPER + r * NA + a;
    scores[idx] = sc;
    boxes[idx] = make_float4(x1, y1, x2, y2);
  }
}

// ---------------------------------------------------------------------------
// K3 (merged topk + sort): exact top-6000 per image via radix select (ties:
// lowest idx, matching lax.top_k stability), compact keys DIRECTLY into the
// LDS sort array, bitonic-sort descending (== lax.top_k order), gather boxes.
// Outputs: sbox[n][6016] sorted boxes (pad zeros), valid[n][128] bitmap.
// ---------------------------------------------------------------------------
__global__ __launch_bounds__(1024) void k_select(const float* __restrict__ scores,
                                                 const float4* __restrict__ boxes,
                                                 float4* __restrict__ sbox,
                                                 u64* __restrict__ valid) {
  __shared__ u64 sk[8192];
  __shared__ unsigned int hist[256];
  __shared__ unsigned int sh_selB, sh_ngt, sh_binc, sh_num;
  const int n = blockIdx.x;
  const int t = threadIdx.x;
  const float* sc = scores + (size_t)n * KPER;

  for (int e = t; e < 8192; e += 1024) sk[e] = 0ull;   /* pad + slots */

  /* radix select (validated r2/r3) */
  unsigned int prefix = 0, prefMask = 0, ngt = 0, neq = 0;
  for (int shift = 24; shift >= 0; shift -= 8) {
    if (t < 256) hist[t] = 0;
    __syncthreads();
    for (int i = t; i < KPER; i += 1024) {
      unsigned int u = ordf(sc[i]);
      if ((u & prefMask) == prefix) atomicAdd(&hist[(u >> shift) & 255], 1u);
    }
    __syncthreads();
    if (t == 0) {
      unsigned int cnt = ngt;
      for (int b = 255; b >= 0; --b) {
        unsigned int c = hist[b];
        if (cnt + c >= (unsigned)PRE) { sh_selB = (unsigned)b; sh_ngt = cnt; sh_binc = c; break; }
        cnt += c;
      }
    }
    __syncthreads();
    prefix |= (sh_selB << shift);
    prefMask |= (0xFFu << shift);
    ngt = sh_ngt;
    neq = sh_binc;
    __syncthreads();
  }
  const unsigned int T = prefix;
  const unsigned int needed = (unsigned)PRE - ngt;
  unsigned int J = 0xFFFFFFFFu;
  if (needed < neq) {
    if (t < 256) hist[t] = 0;
    __syncthreads();
    for (int i = t; i < KPER; i += 1024)
      if (ordf(sc[i]) == T) atomicAdd(&hist[i >> 7], 1u);
    __syncthreads();
    if (t == 0) {
      unsigned int cnt = 0;
      for (int b = 0; b < 256; ++b) {
        unsigned int c = hist[b];
        if (cnt + c >= needed) { sh_selB = (unsigned)b; sh_ngt = needed - cnt; break; }
        cnt += c;
      }
    }
    __syncthreads();
    const unsigned int selH = sh_selB;
    const unsigned int needLow = sh_ngt;
    __syncthreads();
    if (t < 128) hist[t] = 0;
    __syncthreads();
    for (int i = t; i < KPER; i += 1024)
      if (ordf(sc[i]) == T && ((unsigned)(i >> 7)) == selH) atomicAdd(&hist[i & 127], 1u);
    __syncthreads();
    if (t == 0) {
      unsigned int cnt = 0;
      for (int b = 0; b < 128; ++b) {
        unsigned int c = hist[b];
        if (cnt + c >= needLow) { sh_selB = (selH << 7) | (unsigned)b; break; }
        cnt += c;
      }
    }
    __syncthreads();
    J = sh_selB;
  }

  if (t == 0) sh_num = 0;
  __syncthreads();
  for (int i = t; i < KPER; i += 1024) {
    unsigned int u = ordf(sc[i]);
    bool in = (u > T) || (u == T && (unsigned)i <= J);
    if (in) {
      unsigned int p = atomicAdd(&sh_num, 1u);
      sk[p] = (((u64)u) << 32) | (u64)(~(unsigned int)i);
    }
  }
  __syncthreads();

  /* bitonic sort descending, 8192 elems (pad 0 sorts to tail) */
  for (int k = 2; k <= 8192; k <<= 1) {
    for (int j = k >> 1; j > 0; j >>= 1) {
      for (int p = t; p < 4096; p += 1024) {
        const int i = ((p & ~(j - 1)) << 1) | (p & (j - 1));
        const int ip = i | j;
        u64 a = sk[i], b = sk[ip];
        const bool desc = ((i & k) == 0);
        if ((a < b) == desc) { sk[i] = b; sk[ip] = a; }
      }
      __syncthreads();
    }
  }

  /* gather sorted boxes + valid bitmap */
  for (int e = t; e < NCAP; e += 1024) {
    float4 bx = make_float4(0.f, 0.f, 0.f, 0.f);
    if (e < PRE) {
      unsigned idx = ~(unsigned)(sk[e] & 0xFFFFFFFFull);
      bx = boxes[(size_t)n * KPER + idx];
    }
    sbox[(size_t)n * NCAP + e] = bx;
  }
  if (t < 128) {
    u64 w = 0;
    if (t < NW) {
      for (int b = 0; b < 64; ++b) {
        int e = t * 64 + b;
        if (e < PRE && ((sk[e] >> 32) > 0x007FFFFFull)) w |= 1ull << b;
      }
    }
    valid[n * 128 + t] = w;
  }
}

// ---------------------------------------------------------------------------
// K4b: IoU>=0.7 bitmask, UPPER TRIANGLE ONLY (jb >= ib).  Lower-triangle
// words are left uninitialized: the scan ORs whole rows, but lower-triangle
// bits only affect candidates j < (current kept k) -- already decided, never
// re-read.  Triangular grid: blockIdx.x = linearized (ib,jb>=ib) pair.
// IoU arithmetic op-for-op identical to the validated sequential k_nms.
// ---------------------------------------------------------------------------
__global__ __launch_bounds__(64) void k_mask(const float4* __restrict__ sbox,
                                             u64* __restrict__ mask) {
  const int p = blockIdx.x;           /* 0..4464 */
  const int n = blockIdx.y;
  int ib = (int)((189.0 - sqrt(35721.0 - 8.0 * (double)p)) * 0.5);
  while (94 * (ib + 1) - (ib * (ib + 1)) / 2 <= p) ++ib;
  while (94 * ib - ((ib - 1) * ib) / 2 > p) --ib;
  const int jb = ib + (p - (94 * ib - ((ib - 1) * ib) / 2));

  const int r = threadIdx.x;
  const int i = ib * 64 + r;
  __shared__ float4 jbox[64];
  jbox[r] = sbox[(size_t)n * NCAP + jb * 64 + r];
  __syncthreads();
  const float4 pbx = sbox[(size_t)n * NCAP + i];
  const float pa = __fmul_rn(__fsub_rn(pbx.z, pbx.x), __fsub_rn(pbx.w, pbx.y));
  u64 word = 0;
#pragma unroll 8
  for (int b = 0; b < 64; ++b) {
    const float4 q = jbox[b];
    float ltx = fmaxf(pbx.x, q.x);
    float lty = fmaxf(pbx.y, q.y);
    float rbx = fminf(pbx.z, q.z);
    float rby = fminf(pbx.w, q.w);
    float wv = fmaxf(__fsub_rn(rbx, ltx), 0.0f);
    float hv = fmaxf(__fsub_rn(rby, lty), 0.0f);
    float inter = __fmul_rn(wv, hv);
    float a2 = __fmul_rn(__fsub_rn(q.z, q.x), __fsub_rn(q.w, q.y));
    float denom = __fadd_rn(__fsub_rn(__fadd_rn(pa, a2), inter), 1e-9f);
    float iou = __fdiv_rn(inter, denom);
    if (iou >= 0.7f) word |= (1ull << b);
  }
  mask[((size_t)(n * NCAP) + i) * NW + jb] = word;
}

// ---------------------------------------------------------------------------
// K4c: bit-scan.  One wave per image; suppressed set = 94 u64 words (lane l
// owns words 2l, 2l+1).  Walk candidates in sorted order; keep iff valid &
// ~suppressed (== reference argmax sequence); on keep OR row i.  Rows
// group-of-16 prefetched (one dwordx4 per lane per row) so a full group of
// VALU covers each L2 round trip.  <300 keeps -> pad with sorted cand 0.
// ---------------------------------------------------------------------------
__global__ __launch_bounds__(64) void k_scan(const u64* __restrict__ mask,
                                             const u64* __restrict__ valid,
                                             const float4* __restrict__ sbox,
                                             float* __restrict__ out) {
  const int n = blockIdx.x;
  const int lane = threadIdx.x;
  u64 s0 = 0, s1 = 0;
  const u64 v0 = valid[n * 128 + 2 * lane];
  const u64 v1 = valid[n * 128 + 2 * lane + 1];
  const u64* mrow = mask + (size_t)n * NCAP * NW;
  __shared__ int keep_list[POST];
  int kept = 0;

  ulonglong2 cur[16], nxt[16];
#pragma unroll
  for (int r = 0; r < 16; ++r)
    cur[r] = ((const ulonglong2*)(mrow + (size_t)r * NW))[lane];

  for (int g = 0; g < PRE / 16; ++g) {
    if (kept >= POST) break;
    if (g < PRE / 16 - 1) {
#pragma unroll
      for (int r = 0; r < 16; ++r)
        nxt[r] = ((const ulonglong2*)(mrow + (size_t)((g + 1) * 16 + r) * NW))[lane];
    }
#pragma unroll
    for (int r = 0; r < 16; ++r) {
      if (kept < POST) {
        const int i = g * 16 + r;
        const int w = i >> 6;
        const u64 avail = (w & 1) ? (v1 & ~s1) : (v0 & ~s0);
        const unsigned h32 = (unsigned)(avail >> (i & 32));
        const unsigned wrd = __shfl(h32, w >> 1, 64);
        if ((wrd >> (i & 31)) & 1u) {
          if (lane == 0) keep_list[kept] = i;
          ++kept;
          s0 |= cur[r].x;
          s1 |= cur[r].y;
        }
      }
    }
#pragma unroll
    for (int r = 0; r < 16; ++r) cur[r] = nxt[r];
  }
  __syncthreads();

  for (int it = lane; it < POST; it += 64) {
    const int cand = (it < kept) ? keep_list[it] : 0;
    const float4 b = sbox[(size_t)n * NCAP + cand];
    float* orow = out + ((size_t)n * POST + it) * 4;
    orow[0] = b.x; orow[1] = b.y; orow[2] = b.z; orow[3] = b.w;
    out[(size_t)NIMG * POST * 4 + (size_t)n * POST + it] = (float)n;
  }
}

extern "C" void kernel_launch(void* const* d_in, const int* in_sizes, int n_in,
                              void* d_out, int out_size, void* d_ws, size_t ws_size,
                              hipStream_t stream) {
  const float* x    = (const float*)d_in[0];
  const float* w1   = (const float*)d_in[1];
  const float* b1   = (const float*)d_in[2];
  const float* wcls = (const float*)d_in[3];
  const float* bcls = (const float*)d_in[4];
  const float* wbb  = (const float*)d_in[5];
  const float* bbb  = (const float*)d_in[6];
  float* out = (float*)d_out;

  char* ws = (char*)d_ws;
  size_t off = 0;
  float* feat = (float*)(ws + off);               off += (size_t)NIMG * HW * CIN * 4;
  float* scores = (float*)(ws + off);             off += (size_t)NIMG * KPER * 4;
  float4* boxes = (float4*)(ws + off);            off += (size_t)NIMG * KPER * 16;
  float4* sbox = (float4*)(ws + off);             off += (size_t)NIMG * NCAP * 16;
  u64* valid = (u64*)(ws + off);                  off += (size_t)NIMG * 128 * 8;
  u64* mask = (u64*)(ws + off);                   off += (size_t)NIMG * NCAP * NW * 8;
  float* WHT2 = (float*)(ws + off);               off += (size_t)WHT_ELEMS * 4;
  float* bh   = (float*)(ws + off);               off += 256;
  unsigned short* xTh = (unsigned short*)(ws + off); off += XT_BYTES;
  unsigned short* xTl = (unsigned short*)(ws + off); off += XT_BYTES;
  unsigned short* wpk = (unsigned short*)(ws + off); off += WPK_ELEMS * 2;

  k_prep_all<<<PB_TOT, 256, 0, stream>>>((const float4*)x, w1, wcls, bcls, wbb, bbb,
                                         xTh, xTl, wpk, WHT2, bh);
  k_convmfma<<<800, 256, 0, stream>>>(xTh, xTl, wpk, b1, feat);
  k_head<<<(NIMG * HW) / 16, 256, 0, stream>>>(feat, WHT2, bh, scores, boxes);
  k_select<<<NIMG, 1024, 0, stream>>>(scores, boxes, sbox, valid);
  k_mask<<<dim3(NTRI, NIMG), 64, 0, stream>>>(sbox, mask);
  k_scan<<<NIMG, 64, 0, stream>>>(mask, valid, sbox, out);
}